// Round 1
// baseline (6494.460 us; speedup 1.0000x reference)
//
#include <hip/hip_runtime.h>

// SGC 3-layer GCN on MI355X.
// Pipeline: degrees -> norms -> [scatter(scale@gather) -> GEMM(+scale,bias,relu)] x2
//           -> GEMM(128->32) -> scatter(32) -> epilogue(scale+bias).
// fp32 throughout (threshold 1e-3 forbids bf16 MFMA). Atomic f32 scatter-add.

constexpr int FEAT = 128;

__global__ __launch_bounds__(256) void degree_kernel(const int* __restrict__ src,
                                                     const int* __restrict__ dst,
                                                     float* __restrict__ deg_s,
                                                     float* __restrict__ deg_d, int E)
{
    int i = blockIdx.x * 256 + threadIdx.x;
    if (i < E) {
        unsafeAtomicAdd(&deg_s[src[i]], 1.0f);
        unsafeAtomicAdd(&deg_d[dst[i]], 1.0f);
    }
}

__global__ __launch_bounds__(256) void norm_kernel(float* __restrict__ a,
                                                   float* __restrict__ b, int N)
{
    int i = blockIdx.x * 256 + threadIdx.x;
    if (i < N) {
        float da = a[i]; a[i] = (da > 0.f) ? rsqrtf(da) : 0.f;
        float db = b[i]; b[i] = (db > 0.f) ? rsqrtf(db) : 0.f;
    }
}

// Scatter-add: agg[dst[e], :] += h[src[e], :] * norm_src[src[e]]
// One thread per (edge, float4-chunk). 32 consecutive lanes share an edge's row
// for F=128 -> coalesced 512B row reads; atomics land on consecutive addresses.
template<int F>
__global__ __launch_bounds__(256) void scatter_kernel(const float* __restrict__ h,
                                                      const float* __restrict__ nsrc,
                                                      const int* __restrict__ src,
                                                      const int* __restrict__ dst,
                                                      float* __restrict__ agg, int nwork)
{
    constexpr int CH = F / 4;
    int idx = blockIdx.x * 256 + threadIdx.x;
    if (idx >= nwork) return;
    int e = idx / CH;            // CH is power of 2 -> shift
    int c = idx - e * CH;
    int s = src[e];
    int d = dst[e];
    float ns = nsrc[s];
    const float4 v = *reinterpret_cast<const float4*>(h + (size_t)s * F + c * 4);
    float* p = agg + (size_t)d * F + c * 4;
    unsafeAtomicAdd(p + 0, v.x * ns);
    unsafeAtomicAdd(p + 1, v.y * ns);
    unsafeAtomicAdd(p + 2, v.z * ns);
    unsafeAtomicAdd(p + 3, v.w * ns);
}

// C[r, :] = act( rowscale[r] * (A[r, :] @ W) + bias )
// BM=128 rows/block, 512 threads, W(128xNCOL) + padded A tile in LDS.
// Thread tile: 2 rows x (NCOL/8) cols; W reads are bank-conflict-free float4,
// A reads are broadcast across the 8 col-groups with pad-129 to dodge conflicts.
template<int NCOL, bool RELU, bool SCALE, bool BIAS>
__global__ __launch_bounds__(512) void gemm_kernel(const float* __restrict__ A,
                                                   const float* __restrict__ rowscale,
                                                   const float* __restrict__ W,
                                                   const float* __restrict__ bias,
                                                   float* __restrict__ C, int nrows)
{
    constexpr int KK = 128;
    constexpr int BM = 128;
    constexpr int LDA = KK + 1;      // pad: A-row reads hit distinct banks
    constexpr int G = NCOL / 32;     // float4 groups per thread (4 or 1)
    __shared__ alignas(16) float As[BM * LDA];   // 66 KB
    __shared__ alignas(16) float Ws[KK * NCOL];  // 64 KB (NCOL=128) / 16 KB (32)
    const int tid = threadIdx.x;
    const int row0 = blockIdx.x * BM;

    {   // stage W (float4, coalesced)
        const float4* W4 = reinterpret_cast<const float4*>(W);
        float4* Ws4 = reinterpret_cast<float4*>(Ws);
        for (int i = tid; i < KK * NCOL / 4; i += 512) Ws4[i] = W4[i];
    }
    // stage A (scalar into padded tile, coalesced global reads)
    for (int i = tid; i < BM * KK; i += 512) {
        int r = i >> 7, k = i & 127;
        int gr = row0 + r;
        As[r * LDA + k] = (gr < nrows) ? A[(size_t)gr * KK + k] : 0.f;
    }
    __syncthreads();

    const int colgrp = tid & 7;        // 8 col groups x 4*G cols
    const int r0 = (tid >> 3) * 2;     // 64 row groups x 2 rows
    float acc0[G * 4], acc1[G * 4];
    #pragma unroll
    for (int j = 0; j < G * 4; ++j) { acc0[j] = 0.f; acc1[j] = 0.f; }

    const float* Arow = As + r0 * LDA;
    #pragma unroll 4
    for (int k = 0; k < KK; ++k) {
        float a0 = Arow[k];
        float a1 = Arow[LDA + k];
        #pragma unroll
        for (int g = 0; g < G; ++g) {
            float4 w = *reinterpret_cast<const float4*>(Ws + k * NCOL + colgrp * 4 + g * 32);
            acc0[g*4+0] = fmaf(a0, w.x, acc0[g*4+0]);
            acc0[g*4+1] = fmaf(a0, w.y, acc0[g*4+1]);
            acc0[g*4+2] = fmaf(a0, w.z, acc0[g*4+2]);
            acc0[g*4+3] = fmaf(a0, w.w, acc0[g*4+3]);
            acc1[g*4+0] = fmaf(a1, w.x, acc1[g*4+0]);
            acc1[g*4+1] = fmaf(a1, w.y, acc1[g*4+1]);
            acc1[g*4+2] = fmaf(a1, w.z, acc1[g*4+2]);
            acc1[g*4+3] = fmaf(a1, w.w, acc1[g*4+3]);
        }
    }

    #pragma unroll
    for (int rr = 0; rr < 2; ++rr) {
        const float* accp = (rr == 0) ? acc0 : acc1;
        int gr = row0 + r0 + rr;
        if (gr >= nrows) continue;
        float s = SCALE ? rowscale[gr] : 1.f;
        #pragma unroll
        for (int g = 0; g < G; ++g) {
            float4 v;
            v.x = accp[g*4+0] * s;
            v.y = accp[g*4+1] * s;
            v.z = accp[g*4+2] * s;
            v.w = accp[g*4+3] * s;
            if (BIAS) {
                const float* bp = bias + colgrp * 4 + g * 32;
                v.x += bp[0]; v.y += bp[1]; v.z += bp[2]; v.w += bp[3];
            }
            if (RELU) {
                v.x = fmaxf(v.x, 0.f); v.y = fmaxf(v.y, 0.f);
                v.z = fmaxf(v.z, 0.f); v.w = fmaxf(v.w, 0.f);
            }
            *reinterpret_cast<float4*>(C + (size_t)gr * NCOL + colgrp * 4 + g * 32) = v;
        }
    }
}

// out[i, f] = out[i, f] * norm_dst[i] + b3[f]   (32 cols)
__global__ __launch_bounds__(256) void epilogue_kernel(float* __restrict__ out,
                                                       const float* __restrict__ ndst,
                                                       const float* __restrict__ b3, int total)
{
    int i = blockIdx.x * 256 + threadIdx.x;
    if (i < total) {
        int node = i >> 5;
        int col = i & 31;
        out[i] = out[i] * ndst[node] + b3[col];
    }
}

extern "C" void kernel_launch(void* const* d_in, const int* in_sizes, int n_in,
                              void* d_out, int out_size, void* d_ws, size_t ws_size,
                              hipStream_t stream)
{
    const float* x  = (const float*)d_in[0];
    const float* W1 = (const float*)d_in[1];
    const float* b1 = (const float*)d_in[2];
    const float* W2 = (const float*)d_in[3];
    const float* b2 = (const float*)d_in[4];
    const float* W3 = (const float*)d_in[5];
    const float* b3 = (const float*)d_in[6];
    const int*   src = (const int*)d_in[7];
    const int*   dst = (const int*)d_in[8];
    float* out = (float*)d_out;

    const int N = in_sizes[0] / FEAT;   // 100000
    const int E = in_sizes[7];          // 1600000

    float* ws = (float*)d_ws;
    float* norm_src = ws;               // [N]
    float* norm_dst = ws + N;           // [N]
    float* agg      = ws + 2 * (size_t)N;           // [N,128]
    float* h        = agg + (size_t)N * FEAT;       // [N,128]
    float* t        = agg;                           // [N,32] reuse for layer 3

    const int BM = 128;
    const int gemm_blocks = (N + BM - 1) / BM;

    // norms
    hipMemsetAsync(norm_src, 0, 2 * (size_t)N * sizeof(float), stream);
    degree_kernel<<<(E + 255) / 256, 256, 0, stream>>>(src, dst, norm_src, norm_dst, E);
    norm_kernel<<<(N + 255) / 256, 256, 0, stream>>>(norm_src, norm_dst, N);

    // layer 1
    hipMemsetAsync(agg, 0, (size_t)N * FEAT * sizeof(float), stream);
    {
        int nwork = E * (FEAT / 4);
        scatter_kernel<FEAT><<<(nwork + 255) / 256, 256, 0, stream>>>(x, norm_src, src, dst, agg, nwork);
    }
    gemm_kernel<128, true, true, true><<<gemm_blocks, 512, 0, stream>>>(agg, norm_dst, W1, b1, h, N);

    // layer 2
    hipMemsetAsync(agg, 0, (size_t)N * FEAT * sizeof(float), stream);
    {
        int nwork = E * (FEAT / 4);
        scatter_kernel<FEAT><<<(nwork + 255) / 256, 256, 0, stream>>>(h, norm_src, src, dst, agg, nwork);
    }
    gemm_kernel<128, true, true, true><<<gemm_blocks, 512, 0, stream>>>(agg, norm_dst, W2, b2, h, N);

    // layer 3: GEMM first (128->32), then propagate only 32 feats
    gemm_kernel<32, false, false, false><<<gemm_blocks, 512, 0, stream>>>(h, nullptr, W3, nullptr, t, N);
    hipMemsetAsync(out, 0, (size_t)N * 32 * sizeof(float), stream);
    {
        int nwork = E * (32 / 4);
        scatter_kernel<32><<<(nwork + 255) / 256, 256, 0, stream>>>(t, norm_src, src, dst, out, nwork);
    }
    epilogue_kernel<<<(N * 32 + 255) / 256, 256, 0, stream>>>(out, norm_dst, b3, N * 32);
}

// Round 2
// 1011.565 us; speedup vs baseline: 6.4202x; 6.4202x over previous
//
#include <hip/hip_runtime.h>

// SGC 3-layer GCN on MI355X — round 2.
// Scatter-atomics replaced by dst-CSR gather (atomic fp32 scatter was 83% of
// runtime, 3.2 GB HBM write-through per layer). CSR built on device per call:
// int degree count -> single-block prefix scan -> atomic-slot fill.
// Pipeline: degrees -> norms -> scan -> fill ->
//   [gather(+nsrc,+ndst) -> GEMM(+bias,relu) in-place] x2 ->
//   GEMM(128->32) -> gather32(+nsrc,+ndst,+b3) -> out.

constexpr int FEAT = 128;

__global__ __launch_bounds__(256) void degree_kernel(const int* __restrict__ src,
                                                     const int* __restrict__ dst,
                                                     int* __restrict__ deg_out,
                                                     int* __restrict__ deg_in, int E)
{
    int i = blockIdx.x * 256 + threadIdx.x;
    if (i < E) {
        atomicAdd(&deg_out[src[i]], 1);
        atomicAdd(&deg_in[dst[i]], 1);
    }
}

__global__ __launch_bounds__(256) void norm_kernel(const int* __restrict__ dout,
                                                   const int* __restrict__ din,
                                                   float* __restrict__ nsrc,
                                                   float* __restrict__ ndst, int N)
{
    int i = blockIdx.x * 256 + threadIdx.x;
    if (i < N) {
        int a = dout[i], b = din[i];
        nsrc[i] = (a > 0) ? rsqrtf((float)a) : 0.f;
        ndst[i] = (b > 0) ? rsqrtf((float)b) : 0.f;
    }
}

// Single-block exclusive scan of deg_in -> row_start[N+1]; also zeroes cnt.
__global__ __launch_bounds__(1024) void scan_kernel(const int* __restrict__ deg,
                                                    int* __restrict__ row_start,
                                                    int* __restrict__ cnt, int N)
{
    __shared__ int partial[1024];
    const int tid = threadIdx.x;
    const int per = (N + 1023) / 1024;
    const int beg = tid * per;
    const int end = min(beg + per, N);
    int s = 0;
    for (int i = beg; i < end; ++i) s += deg[i];
    partial[tid] = s;
    __syncthreads();
    for (int off = 1; off < 1024; off <<= 1) {
        int v = (tid >= off) ? partial[tid - off] : 0;
        __syncthreads();
        partial[tid] += v;
        __syncthreads();
    }
    int run = (tid == 0) ? 0 : partial[tid - 1];
    for (int i = beg; i < end; ++i) {
        row_start[i] = run;
        run += deg[i];
        cnt[i] = 0;
    }
    if (tid == 1023) row_start[N] = run;
}

__global__ __launch_bounds__(256) void fill_kernel(const int* __restrict__ src,
                                                   const int* __restrict__ dst,
                                                   const int* __restrict__ row_start,
                                                   int* __restrict__ cnt,
                                                   int* __restrict__ csr, int E)
{
    int e = blockIdx.x * 256 + threadIdx.x;
    if (e < E) {
        int d = dst[e];
        int slot = atomicAdd(&cnt[d], 1);
        csr[row_start[d] + slot] = src[e];
    }
}

// out[n,:] = ndst[n] * sum_{j in in(n)} h[csr[j],:] * nsrc[csr[j]]  (+ bias)
// F/4 lanes per node (float4/lane), 256-thread blocks.
template<int F, bool BIAS>
__global__ __launch_bounds__(256) void gather_kernel(const float* __restrict__ h,
                                                     const float* __restrict__ nsrc,
                                                     const float* __restrict__ ndst,
                                                     const int* __restrict__ row_start,
                                                     const int* __restrict__ csr,
                                                     const float* __restrict__ bias,
                                                     float* __restrict__ out, int N)
{
    constexpr int LPN = F / 4;          // lanes per node (32 or 8)
    constexpr int NPB = 256 / LPN;      // nodes per block (8 or 32)
    const int node = blockIdx.x * NPB + threadIdx.x / LPN;
    const int c = (threadIdx.x % LPN) * 4;
    if (node >= N) return;
    const int beg = row_start[node];
    const int end = row_start[node + 1];
    float4 acc = make_float4(0.f, 0.f, 0.f, 0.f);
    int j = beg;
    for (; j + 1 < end; j += 2) {       // 2-way unroll for load ILP
        int s0 = csr[j], s1 = csr[j + 1];
        float n0 = nsrc[s0], n1 = nsrc[s1];
        float4 v0 = *reinterpret_cast<const float4*>(h + (size_t)s0 * F + c);
        float4 v1 = *reinterpret_cast<const float4*>(h + (size_t)s1 * F + c);
        acc.x = fmaf(v0.x, n0, acc.x); acc.y = fmaf(v0.y, n0, acc.y);
        acc.z = fmaf(v0.z, n0, acc.z); acc.w = fmaf(v0.w, n0, acc.w);
        acc.x = fmaf(v1.x, n1, acc.x); acc.y = fmaf(v1.y, n1, acc.y);
        acc.z = fmaf(v1.z, n1, acc.z); acc.w = fmaf(v1.w, n1, acc.w);
    }
    if (j < end) {
        int s0 = csr[j];
        float n0 = nsrc[s0];
        float4 v0 = *reinterpret_cast<const float4*>(h + (size_t)s0 * F + c);
        acc.x = fmaf(v0.x, n0, acc.x); acc.y = fmaf(v0.y, n0, acc.y);
        acc.z = fmaf(v0.z, n0, acc.z); acc.w = fmaf(v0.w, n0, acc.w);
    }
    const float nd = ndst[node];
    float4 o;
    o.x = acc.x * nd; o.y = acc.y * nd; o.z = acc.z * nd; o.w = acc.w * nd;
    if (BIAS) {
        o.x += bias[c]; o.y += bias[c + 1]; o.z += bias[c + 2]; o.w += bias[c + 3];
    }
    *reinterpret_cast<float4*>(out + (size_t)node * F + c) = o;
}

// C[r,:] = act(A[r,:] @ W + bias); safe in-place for NCOL=128 (block stages its
// own rows to LDS before writing them back).
template<int NCOL, bool RELU, bool BIAS>
__global__ __launch_bounds__(512) void gemm_kernel(const float* __restrict__ A,
                                                   const float* __restrict__ W,
                                                   const float* __restrict__ bias,
                                                   float* __restrict__ C, int nrows)
{
    constexpr int KK = 128;
    constexpr int BM = 128;
    constexpr int LDA = KK + 1;
    constexpr int G = NCOL / 32;
    __shared__ alignas(16) float As[BM * LDA];
    __shared__ alignas(16) float Ws[KK * NCOL];
    const int tid = threadIdx.x;
    const int row0 = blockIdx.x * BM;

    {
        const float4* W4 = reinterpret_cast<const float4*>(W);
        float4* Ws4 = reinterpret_cast<float4*>(Ws);
        for (int i = tid; i < KK * NCOL / 4; i += 512) Ws4[i] = W4[i];
    }
    for (int i = tid; i < BM * KK; i += 512) {
        int r = i >> 7, k = i & 127;
        int gr = row0 + r;
        As[r * LDA + k] = (gr < nrows) ? A[(size_t)gr * KK + k] : 0.f;
    }
    __syncthreads();

    const int colgrp = tid & 7;
    const int r0 = (tid >> 3) * 2;
    float acc0[G * 4], acc1[G * 4];
    #pragma unroll
    for (int jj = 0; jj < G * 4; ++jj) { acc0[jj] = 0.f; acc1[jj] = 0.f; }

    const float* Arow = As + r0 * LDA;
    #pragma unroll 4
    for (int k = 0; k < KK; ++k) {
        float a0 = Arow[k];
        float a1 = Arow[LDA + k];
        #pragma unroll
        for (int g = 0; g < G; ++g) {
            float4 w = *reinterpret_cast<const float4*>(Ws + k * NCOL + colgrp * 4 + g * 32);
            acc0[g*4+0] = fmaf(a0, w.x, acc0[g*4+0]);
            acc0[g*4+1] = fmaf(a0, w.y, acc0[g*4+1]);
            acc0[g*4+2] = fmaf(a0, w.z, acc0[g*4+2]);
            acc0[g*4+3] = fmaf(a0, w.w, acc0[g*4+3]);
            acc1[g*4+0] = fmaf(a1, w.x, acc1[g*4+0]);
            acc1[g*4+1] = fmaf(a1, w.y, acc1[g*4+1]);
            acc1[g*4+2] = fmaf(a1, w.z, acc1[g*4+2]);
            acc1[g*4+3] = fmaf(a1, w.w, acc1[g*4+3]);
        }
    }

    #pragma unroll
    for (int rr = 0; rr < 2; ++rr) {
        const float* accp = (rr == 0) ? acc0 : acc1;
        int gr = row0 + r0 + rr;
        if (gr >= nrows) continue;
        #pragma unroll
        for (int g = 0; g < G; ++g) {
            float4 v;
            v.x = accp[g*4+0]; v.y = accp[g*4+1];
            v.z = accp[g*4+2]; v.w = accp[g*4+3];
            if (BIAS) {
                const float* bp = bias + colgrp * 4 + g * 32;
                v.x += bp[0]; v.y += bp[1]; v.z += bp[2]; v.w += bp[3];
            }
            if (RELU) {
                v.x = fmaxf(v.x, 0.f); v.y = fmaxf(v.y, 0.f);
                v.z = fmaxf(v.z, 0.f); v.w = fmaxf(v.w, 0.f);
            }
            *reinterpret_cast<float4*>(C + (size_t)gr * NCOL + colgrp * 4 + g * 32) = v;
        }
    }
}

extern "C" void kernel_launch(void* const* d_in, const int* in_sizes, int n_in,
                              void* d_out, int out_size, void* d_ws, size_t ws_size,
                              hipStream_t stream)
{
    const float* x  = (const float*)d_in[0];
    const float* W1 = (const float*)d_in[1];
    const float* b1 = (const float*)d_in[2];
    const float* W2 = (const float*)d_in[3];
    const float* b2 = (const float*)d_in[4];
    const float* W3 = (const float*)d_in[5];
    const float* b3 = (const float*)d_in[6];
    const int*   src = (const int*)d_in[7];
    const int*   dst = (const int*)d_in[8];
    float* out = (float*)d_out;

    const int N = in_sizes[0] / FEAT;   // 100000
    const int E = in_sizes[7];          // 1600000

    // workspace layout (all regions 16B-aligned)
    char* w = (char*)d_ws;
    float* norm_src  = (float*)w;                      w += (size_t)N * 4;
    float* norm_dst  = (float*)w;                      w += (size_t)N * 4;
    int*   deg_out   = (int*)w;                        w += (size_t)N * 4;
    int*   deg_in    = (int*)w;                        w += (size_t)N * 4;
    int*   row_start = (int*)w;                        w += (size_t)(N + 4) * 4;
    int*   cnt       = (int*)w;                        w += (size_t)N * 4;
    int*   csr       = (int*)w;                        w += (size_t)E * 4;
    float* A         = (float*)w;                      w += (size_t)N * FEAT * 4;
    float* B         = (float*)w;                      /* += N*FEAT*4 */
    float* t         = A;                              // N x 32, reuses A (free at layer 3)

    const int gemm_blocks = (N + 127) / 128;

    // CSR + norms
    hipMemsetAsync(deg_out, 0, 2 * (size_t)N * sizeof(int), stream);
    degree_kernel<<<(E + 255) / 256, 256, 0, stream>>>(src, dst, deg_out, deg_in, E);
    norm_kernel<<<(N + 255) / 256, 256, 0, stream>>>(deg_out, deg_in, norm_src, norm_dst, N);
    scan_kernel<<<1, 1024, 0, stream>>>(deg_in, row_start, cnt, N);
    fill_kernel<<<(E + 255) / 256, 256, 0, stream>>>(src, dst, row_start, cnt, csr, E);

    // layer 1: gather(x)->A, gemm A->A
    gather_kernel<128, false><<<(N * 32 + 255) / 256, 256, 0, stream>>>(
        x, norm_src, norm_dst, row_start, csr, nullptr, A, N);
    gemm_kernel<128, true, true><<<gemm_blocks, 512, 0, stream>>>(A, W1, b1, A, N);

    // layer 2: gather(A)->B, gemm B->B
    gather_kernel<128, false><<<(N * 32 + 255) / 256, 256, 0, stream>>>(
        A, norm_src, norm_dst, row_start, csr, nullptr, B, N);
    gemm_kernel<128, true, true><<<gemm_blocks, 512, 0, stream>>>(B, W2, b2, B, N);

    // layer 3: gemm B->t (128->32), gather32(t)->out with bias
    gemm_kernel<32, false, false><<<gemm_blocks, 512, 0, stream>>>(B, W3, nullptr, t, N);
    gather_kernel<32, true><<<(N * 8 + 255) / 256, 256, 0, stream>>>(
        t, norm_src, norm_dst, row_start, csr, b3, out, N);
}

// Round 3
// 801.052 us; speedup vs baseline: 8.1074x; 1.2628x over previous
//
#include <hip/hip_runtime.h>

// SGC 3-layer GCN on MI355X — round 3.
// r2 fixed scatter-atomics (6494->1011 us). This round: the 230 us single-block
// prefix scan (23% of total, 1 CU busy) becomes a 3-kernel hierarchical scan.
// Pipeline: degrees -> norms -> scan(3 kernels) -> fill ->
//   [gather(+nsrc,+ndst) -> GEMM(+bias,relu)] x2 -> GEMM(128->32) -> gather32.

constexpr int FEAT = 128;

__global__ __launch_bounds__(256) void degree_kernel(const int* __restrict__ src,
                                                     const int* __restrict__ dst,
                                                     int* __restrict__ deg_out,
                                                     int* __restrict__ deg_in, int E)
{
    int i = blockIdx.x * 256 + threadIdx.x;
    if (i < E) {
        atomicAdd(&deg_out[src[i]], 1);
        atomicAdd(&deg_in[dst[i]], 1);
    }
}

__global__ __launch_bounds__(256) void norm_kernel(const int* __restrict__ dout,
                                                   const int* __restrict__ din,
                                                   float* __restrict__ nsrc,
                                                   float* __restrict__ ndst, int N)
{
    int i = blockIdx.x * 256 + threadIdx.x;
    if (i < N) {
        int a = dout[i], b = din[i];
        nsrc[i] = (a > 0) ? rsqrtf((float)a) : 0.f;
        ndst[i] = (b > 0) ? rsqrtf((float)b) : 0.f;
    }
}

// --- hierarchical exclusive scan of deg_in[N] -> row_start[N+1] ---
// pass 1: per-block (256 elems) sums
__global__ __launch_bounds__(256) void scan_sums_kernel(const int* __restrict__ deg,
                                                        int* __restrict__ bsum, int N)
{
    __shared__ int sh[256];
    int i = blockIdx.x * 256 + threadIdx.x;
    int v = (i < N) ? deg[i] : 0;
    sh[threadIdx.x] = v;
    __syncthreads();
    for (int off = 128; off > 0; off >>= 1) {
        if (threadIdx.x < off) sh[threadIdx.x] += sh[threadIdx.x + off];
        __syncthreads();
    }
    if (threadIdx.x == 0) bsum[blockIdx.x] = sh[0];
}

// pass 2: single block scans bsum[nb] (nb <= 1024) -> exclusive offsets; writes row_start[N]=total
__global__ __launch_bounds__(1024) void scan_offsets_kernel(int* __restrict__ bsum,
                                                            int* __restrict__ row_start,
                                                            int nb, int N)
{
    __shared__ int sh[1024];
    int tid = threadIdx.x;
    int v = (tid < nb) ? bsum[tid] : 0;
    sh[tid] = v;
    __syncthreads();
    for (int off = 1; off < 1024; off <<= 1) {
        int t = (tid >= off) ? sh[tid - off] : 0;
        __syncthreads();
        sh[tid] += t;
        __syncthreads();
    }
    if (tid < nb) bsum[tid] = sh[tid] - v;          // exclusive
    if (tid == 1023) row_start[N] = sh[1023];       // total = E
}

// pass 3: per-block exclusive scan + offset -> row_start; zero cnt
__global__ __launch_bounds__(256) void scan_final_kernel(const int* __restrict__ deg,
                                                         const int* __restrict__ bsum,
                                                         int* __restrict__ row_start,
                                                         int* __restrict__ cnt, int N)
{
    __shared__ int sh[256];
    int i = blockIdx.x * 256 + threadIdx.x;
    int tid = threadIdx.x;
    int v = (i < N) ? deg[i] : 0;
    sh[tid] = v;
    __syncthreads();
    for (int off = 1; off < 256; off <<= 1) {
        int t = (tid >= off) ? sh[tid - off] : 0;
        __syncthreads();
        sh[tid] += t;
        __syncthreads();
    }
    if (i < N) {
        row_start[i] = bsum[blockIdx.x] + sh[tid] - v;
        cnt[i] = 0;
    }
}

__global__ __launch_bounds__(256) void fill_kernel(const int* __restrict__ src,
                                                   const int* __restrict__ dst,
                                                   const int* __restrict__ row_start,
                                                   int* __restrict__ cnt,
                                                   int* __restrict__ csr, int E)
{
    int e = blockIdx.x * 256 + threadIdx.x;
    if (e < E) {
        int d = dst[e];
        int slot = atomicAdd(&cnt[d], 1);
        csr[row_start[d] + slot] = src[e];
    }
}

// out[n,:] = ndst[n] * sum_{j in in(n)} h[csr[j],:] * nsrc[csr[j]]  (+ bias)
// F/4 lanes per node (float4/lane), 256-thread blocks, 4-way edge unroll.
template<int F, bool BIAS>
__global__ __launch_bounds__(256) void gather_kernel(const float* __restrict__ h,
                                                     const float* __restrict__ nsrc,
                                                     const float* __restrict__ ndst,
                                                     const int* __restrict__ row_start,
                                                     const int* __restrict__ csr,
                                                     const float* __restrict__ bias,
                                                     float* __restrict__ out, int N)
{
    constexpr int LPN = F / 4;          // lanes per node (32 or 8)
    constexpr int NPB = 256 / LPN;      // nodes per block (8 or 32)
    const int node = blockIdx.x * NPB + threadIdx.x / LPN;
    const int c = (threadIdx.x % LPN) * 4;
    if (node >= N) return;
    const int beg = row_start[node];
    const int end = row_start[node + 1];
    float4 acc = make_float4(0.f, 0.f, 0.f, 0.f);
    int j = beg;
    for (; j + 3 < end; j += 4) {       // 4-way unroll for load ILP
        int s0 = csr[j], s1 = csr[j + 1], s2 = csr[j + 2], s3 = csr[j + 3];
        float n0 = nsrc[s0], n1 = nsrc[s1], n2 = nsrc[s2], n3 = nsrc[s3];
        float4 v0 = *reinterpret_cast<const float4*>(h + (size_t)s0 * F + c);
        float4 v1 = *reinterpret_cast<const float4*>(h + (size_t)s1 * F + c);
        float4 v2 = *reinterpret_cast<const float4*>(h + (size_t)s2 * F + c);
        float4 v3 = *reinterpret_cast<const float4*>(h + (size_t)s3 * F + c);
        acc.x = fmaf(v0.x, n0, acc.x); acc.y = fmaf(v0.y, n0, acc.y);
        acc.z = fmaf(v0.z, n0, acc.z); acc.w = fmaf(v0.w, n0, acc.w);
        acc.x = fmaf(v1.x, n1, acc.x); acc.y = fmaf(v1.y, n1, acc.y);
        acc.z = fmaf(v1.z, n1, acc.z); acc.w = fmaf(v1.w, n1, acc.w);
        acc.x = fmaf(v2.x, n2, acc.x); acc.y = fmaf(v2.y, n2, acc.y);
        acc.z = fmaf(v2.z, n2, acc.z); acc.w = fmaf(v2.w, n2, acc.w);
        acc.x = fmaf(v3.x, n3, acc.x); acc.y = fmaf(v3.y, n3, acc.y);
        acc.z = fmaf(v3.z, n3, acc.z); acc.w = fmaf(v3.w, n3, acc.w);
    }
    for (; j < end; ++j) {
        int s0 = csr[j];
        float n0 = nsrc[s0];
        float4 v0 = *reinterpret_cast<const float4*>(h + (size_t)s0 * F + c);
        acc.x = fmaf(v0.x, n0, acc.x); acc.y = fmaf(v0.y, n0, acc.y);
        acc.z = fmaf(v0.z, n0, acc.z); acc.w = fmaf(v0.w, n0, acc.w);
    }
    const float nd = ndst[node];
    float4 o;
    o.x = acc.x * nd; o.y = acc.y * nd; o.z = acc.z * nd; o.w = acc.w * nd;
    if (BIAS) {
        o.x += bias[c]; o.y += bias[c + 1]; o.z += bias[c + 2]; o.w += bias[c + 3];
    }
    *reinterpret_cast<float4*>(out + (size_t)node * F + c) = o;
}

// C[r,:] = act(A[r,:] @ W + bias); safe in-place for NCOL=128 (block stages its
// own rows to LDS before writing them back).
template<int NCOL, bool RELU, bool BIAS>
__global__ __launch_bounds__(512) void gemm_kernel(const float* __restrict__ A,
                                                   const float* __restrict__ W,
                                                   const float* __restrict__ bias,
                                                   float* __restrict__ C, int nrows)
{
    constexpr int KK = 128;
    constexpr int BM = 128;
    constexpr int LDA = KK + 1;
    constexpr int G = NCOL / 32;
    __shared__ alignas(16) float As[BM * LDA];
    __shared__ alignas(16) float Ws[KK * NCOL];
    const int tid = threadIdx.x;
    const int row0 = blockIdx.x * BM;

    {
        const float4* W4 = reinterpret_cast<const float4*>(W);
        float4* Ws4 = reinterpret_cast<float4*>(Ws);
        for (int i = tid; i < KK * NCOL / 4; i += 512) Ws4[i] = W4[i];
    }
    for (int i = tid; i < BM * KK; i += 512) {
        int r = i >> 7, k = i & 127;
        int gr = row0 + r;
        As[r * LDA + k] = (gr < nrows) ? A[(size_t)gr * KK + k] : 0.f;
    }
    __syncthreads();

    const int colgrp = tid & 7;
    const int r0 = (tid >> 3) * 2;
    float acc0[G * 4], acc1[G * 4];
    #pragma unroll
    for (int jj = 0; jj < G * 4; ++jj) { acc0[jj] = 0.f; acc1[jj] = 0.f; }

    const float* Arow = As + r0 * LDA;
    #pragma unroll 4
    for (int k = 0; k < KK; ++k) {
        float a0 = Arow[k];
        float a1 = Arow[LDA + k];
        #pragma unroll
        for (int g = 0; g < G; ++g) {
            float4 w = *reinterpret_cast<const float4*>(Ws + k * NCOL + colgrp * 4 + g * 32);
            acc0[g*4+0] = fmaf(a0, w.x, acc0[g*4+0]);
            acc0[g*4+1] = fmaf(a0, w.y, acc0[g*4+1]);
            acc0[g*4+2] = fmaf(a0, w.z, acc0[g*4+2]);
            acc0[g*4+3] = fmaf(a0, w.w, acc0[g*4+3]);
            acc1[g*4+0] = fmaf(a1, w.x, acc1[g*4+0]);
            acc1[g*4+1] = fmaf(a1, w.y, acc1[g*4+1]);
            acc1[g*4+2] = fmaf(a1, w.z, acc1[g*4+2]);
            acc1[g*4+3] = fmaf(a1, w.w, acc1[g*4+3]);
        }
    }

    #pragma unroll
    for (int rr = 0; rr < 2; ++rr) {
        const float* accp = (rr == 0) ? acc0 : acc1;
        int gr = row0 + r0 + rr;
        if (gr >= nrows) continue;
        #pragma unroll
        for (int g = 0; g < G; ++g) {
            float4 v;
            v.x = accp[g*4+0]; v.y = accp[g*4+1];
            v.z = accp[g*4+2]; v.w = accp[g*4+3];
            if (BIAS) {
                const float* bp = bias + colgrp * 4 + g * 32;
                v.x += bp[0]; v.y += bp[1]; v.z += bp[2]; v.w += bp[3];
            }
            if (RELU) {
                v.x = fmaxf(v.x, 0.f); v.y = fmaxf(v.y, 0.f);
                v.z = fmaxf(v.z, 0.f); v.w = fmaxf(v.w, 0.f);
            }
            *reinterpret_cast<float4*>(C + (size_t)gr * NCOL + colgrp * 4 + g * 32) = v;
        }
    }
}

extern "C" void kernel_launch(void* const* d_in, const int* in_sizes, int n_in,
                              void* d_out, int out_size, void* d_ws, size_t ws_size,
                              hipStream_t stream)
{
    const float* x  = (const float*)d_in[0];
    const float* W1 = (const float*)d_in[1];
    const float* b1 = (const float*)d_in[2];
    const float* W2 = (const float*)d_in[3];
    const float* b2 = (const float*)d_in[4];
    const float* W3 = (const float*)d_in[5];
    const float* b3 = (const float*)d_in[6];
    const int*   src = (const int*)d_in[7];
    const int*   dst = (const int*)d_in[8];
    float* out = (float*)d_out;

    const int N = in_sizes[0] / FEAT;   // 100000
    const int E = in_sizes[7];          // 1600000
    const int nb = (N + 255) / 256;     // scan blocks (391, must be <= 1024)

    // workspace layout (all regions 16B-aligned)
    char* w = (char*)d_ws;
    float* norm_src  = (float*)w;                      w += (size_t)N * 4;
    float* norm_dst  = (float*)w;                      w += (size_t)N * 4;
    int*   deg_out   = (int*)w;                        w += (size_t)N * 4;
    int*   deg_in    = (int*)w;                        w += (size_t)N * 4;
    int*   row_start = (int*)w;                        w += (size_t)(N + 4) * 4;
    int*   cnt       = (int*)w;                        w += (size_t)N * 4;
    int*   bsum      = (int*)w;                        w += (size_t)1024 * 4;
    int*   csr       = (int*)w;                        w += (size_t)E * 4;
    float* A         = (float*)w;                      w += (size_t)N * FEAT * 4;
    float* B         = (float*)w;                      /* += N*FEAT*4 */
    float* t         = A;                              // N x 32, reuses A

    const int gemm_blocks = (N + 127) / 128;

    // CSR + norms
    hipMemsetAsync(deg_out, 0, 2 * (size_t)N * sizeof(int), stream);
    degree_kernel<<<(E + 255) / 256, 256, 0, stream>>>(src, dst, deg_out, deg_in, E);
    norm_kernel<<<(N + 255) / 256, 256, 0, stream>>>(deg_out, deg_in, norm_src, norm_dst, N);
    scan_sums_kernel<<<nb, 256, 0, stream>>>(deg_in, bsum, N);
    scan_offsets_kernel<<<1, 1024, 0, stream>>>(bsum, row_start, nb, N);
    scan_final_kernel<<<nb, 256, 0, stream>>>(deg_in, bsum, row_start, cnt, N);
    fill_kernel<<<(E + 255) / 256, 256, 0, stream>>>(src, dst, row_start, cnt, csr, E);

    // layer 1: gather(x)->A, gemm A->A
    gather_kernel<128, false><<<(N * 32 + 255) / 256, 256, 0, stream>>>(
        x, norm_src, norm_dst, row_start, csr, nullptr, A, N);
    gemm_kernel<128, true, true><<<gemm_blocks, 512, 0, stream>>>(A, W1, b1, A, N);

    // layer 2: gather(A)->B, gemm B->B
    gather_kernel<128, false><<<(N * 32 + 255) / 256, 256, 0, stream>>>(
        A, norm_src, norm_dst, row_start, csr, nullptr, B, N);
    gemm_kernel<128, true, true><<<gemm_blocks, 512, 0, stream>>>(B, W2, b2, B, N);

    // layer 3: gemm B->t (128->32), gather32(t)->out with bias
    gemm_kernel<32, false, false><<<gemm_blocks, 512, 0, stream>>>(B, W3, nullptr, t, N);
    gather_kernel<32, true><<<(N * 8 + 255) / 256, 256, 0, stream>>>(
        t, norm_src, norm_dst, row_start, csr, b3, out, N);
}

// Round 4
// 685.798 us; speedup vs baseline: 9.4699x; 1.1681x over previous
//
#include <hip/hip_runtime.h>

// SGC 3-layer GCN on MI355X — round 4.
// r3: scan fixed (1011->801 us); gathers now dominate (2x146 us, FETCH 489MB vs
// 819MB logical). This round: gather inputs stored as bf16 pre-scaled by nsrc
// (producer-side), halving gather bytes and shrinking the working set to
// 25.6MB (~L2-aggregate). Accumulation + GEMM math stay fp32.

constexpr int FEAT = 128;

__device__ __forceinline__ unsigned short f2bf(float f) {
    unsigned int u = __builtin_bit_cast(unsigned int, f);
    unsigned int r = (u + 0x7FFFu + ((u >> 16) & 1u)) >> 16;   // RNE
    return (unsigned short)r;
}
__device__ __forceinline__ float bf2f(unsigned short h) {
    unsigned int u = ((unsigned int)h) << 16;
    return __builtin_bit_cast(float, u);
}

__global__ __launch_bounds__(256) void degree_kernel(const int* __restrict__ src,
                                                     const int* __restrict__ dst,
                                                     int* __restrict__ deg_out,
                                                     int* __restrict__ deg_in, int E)
{
    int i = blockIdx.x * 256 + threadIdx.x;
    if (i < E) {
        atomicAdd(&deg_out[src[i]], 1);
        atomicAdd(&deg_in[dst[i]], 1);
    }
}

__global__ __launch_bounds__(256) void norm_kernel(const int* __restrict__ dout,
                                                   const int* __restrict__ din,
                                                   float* __restrict__ nsrc,
                                                   float* __restrict__ ndst, int N)
{
    int i = blockIdx.x * 256 + threadIdx.x;
    if (i < N) {
        int a = dout[i], b = din[i];
        nsrc[i] = (a > 0) ? rsqrtf((float)a) : 0.f;
        ndst[i] = (b > 0) ? rsqrtf((float)b) : 0.f;
    }
}

// xb[n,:] = bf16(x[n,:] * nsrc[n])  — one float4 per thread
__global__ __launch_bounds__(256) void scale_bf16_kernel(const float* __restrict__ x,
                                                         const float* __restrict__ nsrc,
                                                         unsigned short* __restrict__ xb,
                                                         int ngroups)   // N * FEAT/4
{
    int i = blockIdx.x * 256 + threadIdx.x;
    if (i >= ngroups) return;
    int row = i >> 5;                   // FEAT/4 = 32 groups per row
    float ns = nsrc[row];
    float4 v = reinterpret_cast<const float4*>(x)[i];
    ushort4 o;
    o.x = f2bf(v.x * ns); o.y = f2bf(v.y * ns);
    o.z = f2bf(v.z * ns); o.w = f2bf(v.w * ns);
    reinterpret_cast<ushort4*>(xb)[i] = o;
}

// --- hierarchical exclusive scan of deg_in[N] -> row_start[N+1] ---
__global__ __launch_bounds__(256) void scan_sums_kernel(const int* __restrict__ deg,
                                                        int* __restrict__ bsum, int N)
{
    __shared__ int sh[256];
    int i = blockIdx.x * 256 + threadIdx.x;
    int v = (i < N) ? deg[i] : 0;
    sh[threadIdx.x] = v;
    __syncthreads();
    for (int off = 128; off > 0; off >>= 1) {
        if (threadIdx.x < off) sh[threadIdx.x] += sh[threadIdx.x + off];
        __syncthreads();
    }
    if (threadIdx.x == 0) bsum[blockIdx.x] = sh[0];
}

__global__ __launch_bounds__(1024) void scan_offsets_kernel(int* __restrict__ bsum,
                                                            int* __restrict__ row_start,
                                                            int nb, int N)
{
    __shared__ int sh[1024];
    int tid = threadIdx.x;
    int v = (tid < nb) ? bsum[tid] : 0;
    sh[tid] = v;
    __syncthreads();
    for (int off = 1; off < 1024; off <<= 1) {
        int t = (tid >= off) ? sh[tid - off] : 0;
        __syncthreads();
        sh[tid] += t;
        __syncthreads();
    }
    if (tid < nb) bsum[tid] = sh[tid] - v;
    if (tid == 1023) row_start[N] = sh[1023];
}

__global__ __launch_bounds__(256) void scan_final_kernel(const int* __restrict__ deg,
                                                         const int* __restrict__ bsum,
                                                         int* __restrict__ row_start,
                                                         int* __restrict__ cnt, int N)
{
    __shared__ int sh[256];
    int i = blockIdx.x * 256 + threadIdx.x;
    int tid = threadIdx.x;
    int v = (i < N) ? deg[i] : 0;
    sh[tid] = v;
    __syncthreads();
    for (int off = 1; off < 256; off <<= 1) {
        int t = (tid >= off) ? sh[tid - off] : 0;
        __syncthreads();
        sh[tid] += t;
        __syncthreads();
    }
    if (i < N) {
        row_start[i] = bsum[blockIdx.x] + sh[tid] - v;
        cnt[i] = 0;
    }
}

__global__ __launch_bounds__(256) void fill_kernel(const int* __restrict__ src,
                                                   const int* __restrict__ dst,
                                                   const int* __restrict__ row_start,
                                                   int* __restrict__ cnt,
                                                   int* __restrict__ csr, int E)
{
    int e = blockIdx.x * 256 + threadIdx.x;
    if (e < E) {
        int d = dst[e];
        int slot = atomicAdd(&cnt[d], 1);
        csr[row_start[d] + slot] = src[e];
    }
}

// out[n,:] = ndst[n] * sum_{j in in(n)} hb[csr[j],:]  (+ bias)
// hb is bf16, already scaled by nsrc at the producer. F/4 lanes per node,
// 8B (ushort4) per lane per edge, 8-way edge unroll for load MLP.
template<int F, bool BIAS>
__global__ __launch_bounds__(256) void gather_kernel(const unsigned short* __restrict__ hb,
                                                     const float* __restrict__ ndst,
                                                     const int* __restrict__ row_start,
                                                     const int* __restrict__ csr,
                                                     const float* __restrict__ bias,
                                                     float* __restrict__ out, int N)
{
    constexpr int LPN = F / 4;          // lanes per node (32 or 8)
    constexpr int NPB = 256 / LPN;      // nodes per block
    const int node = blockIdx.x * NPB + threadIdx.x / LPN;
    const int c = (threadIdx.x % LPN) * 4;
    if (node >= N) return;
    const int beg = row_start[node];
    const int end = row_start[node + 1];
    float4 acc = make_float4(0.f, 0.f, 0.f, 0.f);
    int j = beg;
    for (; j + 7 < end; j += 8) {
        int s[8];
        #pragma unroll
        for (int u = 0; u < 8; ++u) s[u] = csr[j + u];
        #pragma unroll
        for (int u = 0; u < 8; ++u) {
            ushort4 v = *reinterpret_cast<const ushort4*>(hb + (size_t)s[u] * F + c);
            acc.x += bf2f(v.x); acc.y += bf2f(v.y);
            acc.z += bf2f(v.z); acc.w += bf2f(v.w);
        }
    }
    for (; j < end; ++j) {
        int s0 = csr[j];
        ushort4 v = *reinterpret_cast<const ushort4*>(hb + (size_t)s0 * F + c);
        acc.x += bf2f(v.x); acc.y += bf2f(v.y);
        acc.z += bf2f(v.z); acc.w += bf2f(v.w);
    }
    const float nd = ndst[node];
    float4 o;
    o.x = acc.x * nd; o.y = acc.y * nd; o.z = acc.z * nd; o.w = acc.w * nd;
    if (BIAS) {
        o.x += bias[c]; o.y += bias[c + 1]; o.z += bias[c + 2]; o.w += bias[c + 3];
    }
    *reinterpret_cast<float4*>(out + (size_t)node * F + c) = o;
}

// C[r,:] = act(A[r,:] @ W + bias) [* rowscale] [-> bf16]
// In-place-safe for fp32 NCOL=128 (rows staged to LDS before write-back).
template<int NCOL, bool RELU, bool BIAS, bool SCALE, bool OUTBF16>
__global__ __launch_bounds__(512) void gemm_kernel(const float* __restrict__ A,
                                                   const float* __restrict__ W,
                                                   const float* __restrict__ bias,
                                                   const float* __restrict__ rowscale,
                                                   void* __restrict__ Cv, int nrows)
{
    constexpr int KK = 128;
    constexpr int BM = 128;
    constexpr int LDA = KK + 1;
    constexpr int G = NCOL / 32;
    __shared__ alignas(16) float As[BM * LDA];
    __shared__ alignas(16) float Ws[KK * NCOL];
    const int tid = threadIdx.x;
    const int row0 = blockIdx.x * BM;

    {
        const float4* W4 = reinterpret_cast<const float4*>(W);
        float4* Ws4 = reinterpret_cast<float4*>(Ws);
        for (int i = tid; i < KK * NCOL / 4; i += 512) Ws4[i] = W4[i];
    }
    for (int i = tid; i < BM * KK; i += 512) {
        int r = i >> 7, k = i & 127;
        int gr = row0 + r;
        As[r * LDA + k] = (gr < nrows) ? A[(size_t)gr * KK + k] : 0.f;
    }
    __syncthreads();

    const int colgrp = tid & 7;
    const int r0 = (tid >> 3) * 2;
    float acc0[G * 4], acc1[G * 4];
    #pragma unroll
    for (int jj = 0; jj < G * 4; ++jj) { acc0[jj] = 0.f; acc1[jj] = 0.f; }

    const float* Arow = As + r0 * LDA;
    #pragma unroll 4
    for (int k = 0; k < KK; ++k) {
        float a0 = Arow[k];
        float a1 = Arow[LDA + k];
        #pragma unroll
        for (int g = 0; g < G; ++g) {
            float4 w = *reinterpret_cast<const float4*>(Ws + k * NCOL + colgrp * 4 + g * 32);
            acc0[g*4+0] = fmaf(a0, w.x, acc0[g*4+0]);
            acc0[g*4+1] = fmaf(a0, w.y, acc0[g*4+1]);
            acc0[g*4+2] = fmaf(a0, w.z, acc0[g*4+2]);
            acc0[g*4+3] = fmaf(a0, w.w, acc0[g*4+3]);
            acc1[g*4+0] = fmaf(a1, w.x, acc1[g*4+0]);
            acc1[g*4+1] = fmaf(a1, w.y, acc1[g*4+1]);
            acc1[g*4+2] = fmaf(a1, w.z, acc1[g*4+2]);
            acc1[g*4+3] = fmaf(a1, w.w, acc1[g*4+3]);
        }
    }

    #pragma unroll
    for (int rr = 0; rr < 2; ++rr) {
        const float* accp = (rr == 0) ? acc0 : acc1;
        int gr = row0 + r0 + rr;
        if (gr >= nrows) continue;
        float s = SCALE ? rowscale[gr] : 1.f;
        #pragma unroll
        for (int g = 0; g < G; ++g) {
            float4 v;
            v.x = accp[g*4+0]; v.y = accp[g*4+1];
            v.z = accp[g*4+2]; v.w = accp[g*4+3];
            if (BIAS) {
                const float* bp = bias + colgrp * 4 + g * 32;
                v.x += bp[0]; v.y += bp[1]; v.z += bp[2]; v.w += bp[3];
            }
            if (RELU) {
                v.x = fmaxf(v.x, 0.f); v.y = fmaxf(v.y, 0.f);
                v.z = fmaxf(v.z, 0.f); v.w = fmaxf(v.w, 0.f);
            }
            if (SCALE) { v.x *= s; v.y *= s; v.z *= s; v.w *= s; }
            size_t off = (size_t)gr * NCOL + colgrp * 4 + g * 32;
            if (OUTBF16) {
                ushort4 o;
                o.x = f2bf(v.x); o.y = f2bf(v.y); o.z = f2bf(v.z); o.w = f2bf(v.w);
                *reinterpret_cast<ushort4*>((unsigned short*)Cv + off) = o;
            } else {
                *reinterpret_cast<float4*>((float*)Cv + off) = v;
            }
        }
    }
}

extern "C" void kernel_launch(void* const* d_in, const int* in_sizes, int n_in,
                              void* d_out, int out_size, void* d_ws, size_t ws_size,
                              hipStream_t stream)
{
    const float* x  = (const float*)d_in[0];
    const float* W1 = (const float*)d_in[1];
    const float* b1 = (const float*)d_in[2];
    const float* W2 = (const float*)d_in[3];
    const float* b2 = (const float*)d_in[4];
    const float* W3 = (const float*)d_in[5];
    const float* b3 = (const float*)d_in[6];
    const int*   src = (const int*)d_in[7];
    const int*   dst = (const int*)d_in[8];
    float* out = (float*)d_out;

    const int N = in_sizes[0] / FEAT;   // 100000
    const int E = in_sizes[7];          // 1600000
    const int nb = (N + 255) / 256;     // 391 <= 1024

    // workspace layout (16B-aligned regions)
    char* w = (char*)d_ws;
    float* norm_src  = (float*)w;                  w += (size_t)N * 4;
    float* norm_dst  = (float*)w;                  w += (size_t)N * 4;
    int*   deg_out   = (int*)w;                    w += (size_t)N * 4;
    int*   deg_in    = (int*)w;                    w += (size_t)N * 4;
    int*   row_start = (int*)w;                    w += (size_t)(N + 4) * 4;
    int*   cnt       = (int*)w;                    w += (size_t)N * 4;
    int*   bsum      = (int*)w;                    w += (size_t)1024 * 4;
    int*   csr       = (int*)w;                    w += (size_t)E * 4;
    unsigned short* hb = (unsigned short*)w;       w += (size_t)N * FEAT * 2;  // bf16 gather input
    unsigned short* tb = (unsigned short*)w;       w += (size_t)N * 32 * 2;    // bf16 layer-3 input
    float* agg       = (float*)w;                  /* N*FEAT*4; in-place GEMM2 */

    const int gemm_blocks = (N + 127) / 128;

    // CSR + norms
    hipMemsetAsync(deg_out, 0, 2 * (size_t)N * sizeof(int), stream);
    degree_kernel<<<(E + 255) / 256, 256, 0, stream>>>(src, dst, deg_out, deg_in, E);
    norm_kernel<<<(N + 255) / 256, 256, 0, stream>>>(deg_out, deg_in, norm_src, norm_dst, N);
    scan_sums_kernel<<<nb, 256, 0, stream>>>(deg_in, bsum, N);
    scan_offsets_kernel<<<1, 1024, 0, stream>>>(bsum, row_start, nb, N);
    scan_final_kernel<<<nb, 256, 0, stream>>>(deg_in, bsum, row_start, cnt, N);
    fill_kernel<<<(E + 255) / 256, 256, 0, stream>>>(src, dst, row_start, cnt, csr, E);

    // layer 1: xb = bf16(x*nsrc); gather(xb)->agg; gemm agg -> hb (bf16, *nsrc)
    scale_bf16_kernel<<<(N * 32 + 255) / 256, 256, 0, stream>>>(x, norm_src, hb, N * 32);
    gather_kernel<128, false><<<(N * 32 + 255) / 256, 256, 0, stream>>>(
        hb, norm_dst, row_start, csr, nullptr, agg, N);
    gemm_kernel<128, true, true, true, true><<<gemm_blocks, 512, 0, stream>>>(
        agg, W1, b1, norm_src, hb, N);

    // layer 2: gather(hb)->agg; gemm agg -> agg (fp32, in-place)
    gather_kernel<128, false><<<(N * 32 + 255) / 256, 256, 0, stream>>>(
        hb, norm_dst, row_start, csr, nullptr, agg, N);
    gemm_kernel<128, true, true, false, false><<<gemm_blocks, 512, 0, stream>>>(
        agg, W2, b2, nullptr, agg, N);

    // layer 3: gemm agg -> tb (bf16, 128->32, *nsrc); gather32(tb)->out (+b3)
    gemm_kernel<32, false, false, true, true><<<gemm_blocks, 512, 0, stream>>>(
        agg, W3, nullptr, norm_src, tb, N);
    gather_kernel<32, true><<<(N * 8 + 255) / 256, 256, 0, stream>>>(
        tb, norm_dst, row_start, csr, b3, out, N);
}